// Round 5
// baseline (1259.584 us; speedup 1.0000x reference)
//
#include <hip/hip_runtime.h>

typedef unsigned short ushort_t;
typedef __attribute__((ext_vector_type(8))) short short8;
typedef __attribute__((ext_vector_type(4))) float floatx4;

#define BSZ   512
#define UNITS 256
#define IMG   64
#define STEPS 10
#define GATES 1024
// ext layout per batch row: [patches 9216 | h_dec 256 | h_dec 256 | h_enc 256]
#define KENC  9984
#define ESPLIT 16   // 312 kt = 8 chunks of 20 + 8 of 19  -> 512 blocks = 2/CU
#define DSPLIT 8    // 16 kt = 8 chunks of 2              -> 256 blocks
#define CSPLIT 2    // canvas: 8 kt = 2 chunks of 4 (atomic epilogue)

__device__ inline float b2f(ushort_t u) {
  union { float f; unsigned int i; } v; v.i = ((unsigned int)u) << 16; return v.f;
}
__device__ inline ushort_t f2b(float f) {
  unsigned int u = __float_as_uint(f);
  u += 0x7fffu + ((u >> 16) & 1u);          // round-to-nearest-even
  return (ushort_t)(u >> 16);
}
__device__ inline float sigm(float x) { return 1.f / (1.f + __expf(-x)); }

// ---------------------------------------------------------------------------
// Weight pre-transpose + hi/lo split:
// ohi/olo[n][k] = split( (k<ksplit ? s0[k][n] : s1[k-ksplit][n]) )
// ---------------------------------------------------------------------------
__global__ __launch_bounds__(256) void k_prep(const float* __restrict__ s0,
                                              const float* __restrict__ s1,
                                              int ksplit, int src_ld, int out_ld,
                                              ushort_t* __restrict__ ohi,
                                              ushort_t* __restrict__ olo) {
  __shared__ float T[64][68];
  int t = threadIdx.x;
  int k0 = blockIdx.x * 64, n0 = blockIdx.y * 64;
  int r = t >> 2, seg = t & 3;
  int k = k0 + r;
  const float* src = (k < ksplit) ? (s0 + (size_t)k * src_ld)
                                  : (s1 + (size_t)(k - ksplit) * src_ld);
#pragma unroll
  for (int j = 0; j < 4; ++j)
    *(float4*)&T[r][seg * 16 + j * 4] = *(const float4*)(src + n0 + seg * 16 + j * 4);
  __syncthreads();
  ushort_t thi[16], tlo[16];
#pragma unroll
  for (int j = 0; j < 16; ++j) {
    float v = T[seg * 16 + j][r];
    ushort_t h = f2b(v);
    thi[j] = h;
    tlo[j] = f2b(v - b2f(h));
  }
  size_t off = (size_t)(n0 + r) * out_ld + k0 + seg * 16;
  *(uint4*)(ohi + off)     = *(const uint4*)&thi[0];
  *(uint4*)(ohi + off + 8) = *(const uint4*)&thi[8];
  *(uint4*)(olo + off)     = *(const uint4*)&tlo[0];
  *(uint4*)(olo + off + 8) = *(const uint4*)&tlo[8];
}

// ---------------------------------------------------------------------------
// x_hat = x - sigmoid(canvas); 3x3/stride2/SAME patches -> ext hi/lo
// ---------------------------------------------------------------------------
__global__ __launch_bounds__(256) void k_patches(const float* __restrict__ x,
                                                 const float* __restrict__ canvas,
                                                 ushort_t* __restrict__ ehi,
                                                 ushort_t* __restrict__ elo) {
  int tid = blockIdx.x * 256 + threadIdx.x;       // 512*1024 threads
  int b = tid >> 10;
  int p = tid & 1023;
  int oi = p >> 5, oj = p & 31;
  const float* xb = x + (size_t)b * (IMG * IMG);
  const float* cb = canvas + (size_t)b * (IMG * IMG);
  size_t base = (size_t)b * KENC + (size_t)p * 9;
#pragma unroll
  for (int di = 0; di < 3; ++di) {
    int r = 2 * oi + di;                          // SAME pad: lo=0, hi=1
#pragma unroll
    for (int dj = 0; dj < 3; ++dj) {
      int c = 2 * oj + dj;
      float v = 0.f;
      if (r < IMG && c < IMG)
        v = xb[r * IMG + c] - sigm(cb[r * IMG + c]);
      ushort_t h = f2b(v);
      ehi[base + di * 3 + dj] = h;
      elo[base + di * 3 + dj] = f2b(v - b2f(h));
    }
  }
}

// ---------------------------------------------------------------------------
// Fused 3-product split-precision GEMM: C[M,N] fp32 = A[M,K] * Bt[N,K]^T where
// A ~ Ahi+Alo, B ~ Bhi+Blo (bf16 hi/lo); hihi+hilo+lohi in one fp32 acc.
// 128x128 tile, 4 waves (2x2), 48 MFMA/kt/wave, double-buffered prefetch.
// Split-K (possibly uneven): z gets base_kt + (z<extra) iters.
// mode 0: C_part[z] = acc ; mode 1: atomicAdd(C, acc (+bias if z==0))
// ---------------------------------------------------------------------------
#define TM 128
#define TN 128
#define BK 32

#define GLL(g, l) __builtin_amdgcn_global_load_lds(                      \
    (const __attribute__((address_space(1))) void*)(g),                  \
    (__attribute__((address_space(3))) void*)(l), 16, 0, 0)

__global__ __launch_bounds__(256, 2) void gemm128(
    const ushort_t* __restrict__ Ahi, const ushort_t* __restrict__ Alo, int lda,
    const ushort_t* __restrict__ Bhi, const ushort_t* __restrict__ Blo, int ldbt,
    float* __restrict__ C, int ldc, int base_kt, int extra,
    const float* __restrict__ bias, int mode) {
  __shared__ ushort_t ls[2][4][TM * BK];   // [buf][Ah,Al,Bh,Bl] : 64 KiB
  int t = threadIdx.x;
  int m0 = blockIdx.y * TM, n0 = blockIdx.x * TN;
  int z = blockIdx.z;
  int kiters = base_kt + (z < extra ? 1 : 0);
  int kstart = (z * base_kt + (z < extra ? z : extra)) * BK;
  int lane = t & 63, w = t >> 6;
  int wm = w >> 1, wn = w & 1;
  int q = lane >> 4, c16 = lane & 15;

  const ushort_t* pAh = Ahi + (size_t)(m0 + (t >> 2)) * lda + kstart + (t & 3) * 8;
  const ushort_t* pAl = Alo + (size_t)(m0 + (t >> 2)) * lda + kstart + (t & 3) * 8;
  const ushort_t* pBh = Bhi + (size_t)(n0 + (t >> 2)) * ldbt + kstart + (t & 3) * 8;
  const ushort_t* pBl = Blo + (size_t)(n0 + (t >> 2)) * ldbt + kstart + (t & 3) * 8;
  const size_t a64 = (size_t)64 * lda, b64 = (size_t)64 * ldbt;
  const int d0 = t * 8;                    // lds dest (ushorts): wave-uniform + lane*16B

  floatx4 acc[4][4];
#pragma unroll
  for (int i = 0; i < 4; ++i)
#pragma unroll
    for (int j = 0; j < 4; ++j) acc[i][j] = floatx4{0.f, 0.f, 0.f, 0.f};

  // prologue: stage tile 0 into buf 0
  GLL(pAh, &ls[0][0][d0]); GLL(pAh + a64, &ls[0][0][d0 + 2048]);
  GLL(pAl, &ls[0][1][d0]); GLL(pAl + a64, &ls[0][1][d0 + 2048]);
  GLL(pBh, &ls[0][2][d0]); GLL(pBh + b64, &ls[0][2][d0 + 2048]);
  GLL(pBl, &ls[0][3][d0]); GLL(pBl + b64, &ls[0][3][d0 + 2048]);
  pAh += BK; pAl += BK; pBh += BK; pBl += BK;
  __syncthreads();

  for (int kt = 0; kt < kiters; ++kt) {
    int cur = kt & 1, nxt = cur ^ 1;
    if (kt + 1 < kiters) {                 // prefetch kt+1 — in flight during MFMAs
      GLL(pAh, &ls[nxt][0][d0]); GLL(pAh + a64, &ls[nxt][0][d0 + 2048]);
      GLL(pAl, &ls[nxt][1][d0]); GLL(pAl + a64, &ls[nxt][1][d0 + 2048]);
      GLL(pBh, &ls[nxt][2][d0]); GLL(pBh + b64, &ls[nxt][2][d0 + 2048]);
      GLL(pBl, &ls[nxt][3][d0]); GLL(pBl + b64, &ls[nxt][3][d0 + 2048]);
      pAh += BK; pAl += BK; pBh += BK; pBl += BK;
    }
    short8 ah[4], al[4], bh[4], bl[4];
#pragma unroll
    for (int i = 0; i < 4; ++i) {
      int ra = (wm * 64 + i * 16 + c16) * BK + q * 8;
      int rb = (wn * 64 + i * 16 + c16) * BK + q * 8;
      ah[i] = *(const short8*)&ls[cur][0][ra];
      al[i] = *(const short8*)&ls[cur][1][ra];
      bh[i] = *(const short8*)&ls[cur][2][rb];
      bl[i] = *(const short8*)&ls[cur][3][rb];
    }
#pragma unroll
    for (int mi = 0; mi < 4; ++mi)
#pragma unroll
      for (int ni = 0; ni < 4; ++ni) {
        acc[mi][ni] = __builtin_amdgcn_mfma_f32_16x16x32_bf16(ah[mi], bh[ni], acc[mi][ni], 0, 0, 0);
        acc[mi][ni] = __builtin_amdgcn_mfma_f32_16x16x32_bf16(ah[mi], bl[ni], acc[mi][ni], 0, 0, 0);
        acc[mi][ni] = __builtin_amdgcn_mfma_f32_16x16x32_bf16(al[mi], bh[ni], acc[mi][ni], 0, 0, 0);
      }
    __syncthreads();   // drains prefetch vmcnt + everyone's ds_reads of `cur`
  }

  float* Cz = C + (size_t)z * BSZ * ldc;
#pragma unroll
  for (int mi = 0; mi < 4; ++mi)
#pragma unroll
    for (int ni = 0; ni < 4; ++ni) {
      int n = n0 + wn * 64 + ni * 16 + c16;
      int mb = m0 + wm * 64 + mi * 16 + q * 4;
      float bv = (mode == 1 && bias && z == 0) ? bias[n] : 0.f;
#pragma unroll
      for (int r = 0; r < 4; ++r) {
        int m = mb + r;
        if (mode == 1) atomicAdd(&C[(size_t)m * ldc + n], acc[mi][ni][r] + bv);
        else           Cz[(size_t)m * ldc + n] = acc[mi][ni][r];
      }
    }
}

// ---------------------------------------------------------------------------
// Encoder LSTM elementwise + attention softmax + glimpse; block = batch row
// ---------------------------------------------------------------------------
__global__ __launch_bounds__(256) void k_enc(const float* __restrict__ zparts, int S,
                                             const float* __restrict__ ebias,
                                             float* __restrict__ c_enc,
                                             ushort_t* __restrict__ ehi,
                                             ushort_t* __restrict__ elo,
                                             const float* __restrict__ Wenc,
                                             const float* __restrict__ benc,
                                             ushort_t* __restrict__ dhi,
                                             ushort_t* __restrict__ dlo) {
  int b = blockIdx.x, u = threadIdx.x;
  float zi = ebias[u],       zf = ebias[u + 256];
  float zg = ebias[u + 512], zo = ebias[u + 768];
  for (int s = 0; s < S; ++s) {
    const float* z = zparts + ((size_t)s * BSZ + b) * GATES;
    zi += z[u]; zf += z[u + 256]; zg += z[u + 512]; zo += z[u + 768];
  }
  float c = c_enc[b * UNITS + u];
  float cn = sigm(zf) * c + sigm(zi) * tanhf(zg);
  float h = sigm(zo) * tanhf(cn);
  c_enc[b * UNITS + u] = cn;
  ushort_t hh = f2b(h);
  ehi[(size_t)b * KENC + 9728 + u] = hh;
  elo[(size_t)b * KENC + 9728 + u] = f2b(h - b2f(hh));

  __shared__ float sh[UNITS];
  __shared__ float slog[10];
  sh[u] = h;
  __syncthreads();
  if (u < 64) {
    float acc[10];
#pragma unroll
    for (int j = 0; j < 10; ++j) acc[j] = 0.f;
    for (int qq = 0; qq < 4; ++qq) {
      float hv = sh[u + qq * 64];
      const float* wr = Wenc + (u + qq * 64) * 10;
#pragma unroll
      for (int j = 0; j < 10; ++j) acc[j] += hv * wr[j];
    }
    for (int off = 32; off > 0; off >>= 1)
#pragma unroll
      for (int j = 0; j < 10; ++j) acc[j] += __shfl_down(acc[j], off);
    if (u == 0)
      for (int j = 0; j < 10; ++j) slog[j] = acc[j] + benc[j];
  }
  __syncthreads();
  float mx = slog[0];
  for (int j = 1; j < 10; ++j) mx = fmaxf(mx, slog[j]);
  float e[10], se = 0.f;
  for (int j = 0; j < 10; ++j) { e[j] = __expf(slog[j] - mx); se += e[j]; }
  float inv = 1.f / se;
  const float* wr = Wenc + u * 10;
  float zz = 0.f;
  for (int j = 0; j < 10; ++j) zz += e[j] * inv * wr[j];   // attn @ W_enc.T
  ushort_t zh = f2b(zz);
  dhi[(size_t)b * 512 + u] = zh;
  dlo[(size_t)b * 512 + u] = f2b(zz - b2f(zh));
}

// ---------------------------------------------------------------------------
// Decoder LSTM elementwise; writes h_dec (hi/lo) into dec_in and ext
// ---------------------------------------------------------------------------
__global__ __launch_bounds__(256) void k_dec(const float* __restrict__ zparts, int S,
                                             const float* __restrict__ dbias,
                                             float* __restrict__ c_dec,
                                             ushort_t* __restrict__ dhi,
                                             ushort_t* __restrict__ dlo,
                                             ushort_t* __restrict__ ehi,
                                             ushort_t* __restrict__ elo) {
  int b = blockIdx.x, u = threadIdx.x;
  float zi = dbias[u],       zf = dbias[u + 256];
  float zg = dbias[u + 512], zo = dbias[u + 768];
  for (int s = 0; s < S; ++s) {
    const float* z = zparts + ((size_t)s * BSZ + b) * GATES;
    zi += z[u]; zf += z[u + 256]; zg += z[u + 512]; zo += z[u + 768];
  }
  float c = c_dec[b * UNITS + u];
  float cn = sigm(zf) * c + sigm(zi) * tanhf(zg);
  float h = sigm(zo) * tanhf(cn);
  c_dec[b * UNITS + u] = cn;
  ushort_t hh = f2b(h);
  ushort_t hl = f2b(h - b2f(hh));
  dhi[(size_t)b * 512 + 256 + u] = hh;
  dlo[(size_t)b * 512 + 256 + u] = hl;
  ehi[(size_t)b * KENC + 9216 + u] = hh;
  elo[(size_t)b * KENC + 9216 + u] = hl;
  ehi[(size_t)b * KENC + 9472 + u] = hh;
  elo[(size_t)b * KENC + 9472 + u] = hl;
}

// ---------------------------------------------------------------------------
extern "C" void kernel_launch(void* const* d_in, const int* in_sizes, int n_in,
                              void* d_out, int out_size, void* d_ws, size_t ws_size,
                              hipStream_t stream) {
  const float* x     = (const float*)d_in[0];
  const float* ek    = (const float*)d_in[1];   // [9728,1024]
  const float* er    = (const float*)d_in[2];   // [256,1024]
  const float* ebias = (const float*)d_in[3];
  const float* dk    = (const float*)d_in[4];   // [256,1024]
  const float* dr    = (const float*)d_in[5];   // [256,1024]
  const float* dbias = (const float*)d_in[6];
  const float* Wenc  = (const float*)d_in[7];   // [256,10]
  const float* benc  = (const float*)d_in[8];
  const float* Wdec  = (const float*)d_in[9];   // [256,4096]
  const float* bdec  = (const float*)d_in[10];

  float* canvas = (float*)d_out;                // [512, 4096] — persistent canvas

  char* p = (char*)d_ws;
  float* c_enc  = (float*)p;        p += (size_t)BSZ * UNITS * 4;
  float* c_dec  = (float*)p;        p += (size_t)BSZ * UNITS * 4;
  float* zep    = (float*)p;        p += (size_t)ESPLIT * BSZ * GATES * 4;  // enc split-K parts
  float* zdp    = (float*)p;        p += (size_t)DSPLIT * BSZ * GATES * 4;  // dec split-K parts
  ushort_t* ehi = (ushort_t*)p;     p += (size_t)BSZ * KENC * 2;
  ushort_t* elo = (ushort_t*)p;     p += (size_t)BSZ * KENC * 2;
  ushort_t* dhi = (ushort_t*)p;     p += (size_t)BSZ * 512 * 2;
  ushort_t* dlo = (ushort_t*)p;     p += (size_t)BSZ * 512 * 2;
  ushort_t* Wet_hi = (ushort_t*)p;  p += (size_t)GATES * KENC * 2;      // [1024][9984]
  ushort_t* Wet_lo = (ushort_t*)p;  p += (size_t)GATES * KENC * 2;
  ushort_t* Wdt_hi = (ushort_t*)p;  p += (size_t)GATES * 512 * 2;       // [1024][512]
  ushort_t* Wdt_lo = (ushort_t*)p;  p += (size_t)GATES * 512 * 2;
  ushort_t* Wct_hi = (ushort_t*)p;  p += (size_t)4096 * UNITS * 2;      // [4096][256]
  ushort_t* Wct_lo = (ushort_t*)p;  p += (size_t)4096 * UNITS * 2;

  hipMemsetAsync(canvas, 0, (size_t)BSZ * 4096 * 4, stream);
  hipMemsetAsync(c_enc,  0, (size_t)BSZ * UNITS * 4, stream);
  hipMemsetAsync(c_dec,  0, (size_t)BSZ * UNITS * 4, stream);
  hipMemsetAsync(ehi,    0, (size_t)BSZ * KENC * 2, stream);
  hipMemsetAsync(elo,    0, (size_t)BSZ * KENC * 2, stream);
  hipMemsetAsync(dhi,    0, (size_t)BSZ * 512 * 2, stream);
  hipMemsetAsync(dlo,    0, (size_t)BSZ * 512 * 2, stream);

  // weight transposes + hi/lo split (once per launch)
  k_prep<<<dim3(KENC / 64, GATES / 64), 256, 0, stream>>>(ek, er, 9728, 1024, KENC, Wet_hi, Wet_lo);
  k_prep<<<dim3(512 / 64, GATES / 64), 256, 0, stream>>>(dk, dr, 256, 1024, 512, Wdt_hi, Wdt_lo);
  k_prep<<<dim3(256 / 64, 4096 / 64), 256, 0, stream>>>(Wdec, Wdec, 1 << 30, 4096, 256, Wct_hi, Wct_lo);

  for (int s = 0; s < STEPS; ++s) {
    k_patches<<<2048, 256, 0, stream>>>(x, canvas, ehi, elo);
    // z_enc = ext @ Wet^T (M=512,K=9984,N=1024), fused 3-product, split-K 16 (8x20+8x19)
    gemm128<<<dim3(GATES / 128, BSZ / 128, ESPLIT), 256, 0, stream>>>(
        ehi, elo, KENC, Wet_hi, Wet_lo, KENC, zep, GATES, 19, 8, nullptr, 0);
    k_enc<<<BSZ, 256, 0, stream>>>(zep, ESPLIT, ebias, c_enc, ehi, elo, Wenc, benc, dhi, dlo);
    // z_dec = [z|h_dec] @ Wdt^T (M=512,K=512,N=1024), fused, split-K 8x2
    gemm128<<<dim3(GATES / 128, BSZ / 128, DSPLIT), 256, 0, stream>>>(
        dhi, dlo, 512, Wdt_hi, Wdt_lo, 512, zdp, GATES, 2, 0, nullptr, 0);
    k_dec<<<BSZ, 256, 0, stream>>>(zdp, DSPLIT, dbias, c_dec, dhi, dlo, ehi, elo);
    // canvas += h_dec @ Wct^T + b_dec (M=512,K=256,N=4096), split-K 2x4, atomic
    gemm128<<<dim3(4096 / 128, BSZ / 128, CSPLIT), 256, 0, stream>>>(
        dhi + 256, dlo + 256, 512, Wct_hi, Wct_lo, 256, canvas, 4096, 4, 0, bdec, 1);
  }
}

// Round 6
// 944.256 us; speedup vs baseline: 1.3339x; 1.3339x over previous
//
#include <hip/hip_runtime.h>

typedef unsigned short ushort_t;
typedef __attribute__((ext_vector_type(8))) short short8;
typedef __attribute__((ext_vector_type(4))) float floatx4;

#define BSZ   512
#define UNITS 256
#define IMG   64
#define STEPS 10
#define GATES 1024
// folded ext layout per batch row: [x_hat 4096 | h_dec 256 | h_enc 256]
#define KENC  4608
#define ESPLIT 8    // 144 kt = 8 chunks of 18 -> 256 blocks
#define DSPLIT 4    // 16 kt = 4 chunks of 4   -> 128 blocks

__device__ inline float b2f(ushort_t u) {
  union { float f; unsigned int i; } v; v.i = ((unsigned int)u) << 16; return v.f;
}
__device__ inline ushort_t f2b(float f) {
  unsigned int u = __float_as_uint(f);
  u += 0x7fffu + ((u >> 16) & 1u);          // round-to-nearest-even
  return (ushort_t)(u >> 16);
}
__device__ inline float sigm(float x) { return 1.f / (1.f + __expf(-x)); }

// ---------------------------------------------------------------------------
// Fold patch weights into per-pixel weights + transpose + hi/lo split.
// W'[n][pix] = sum over patches (oi,di),(oj,dj) with 2oi+di=r, 2oj+dj=c of
//   ek[((oi*32+oj)*9 + di*3+dj)][n].   grid: (64 pix-tiles, 16 n-tiles)
// ---------------------------------------------------------------------------
__global__ __launch_bounds__(256) void k_prep_pix(const float* __restrict__ ek,
                                                  ushort_t* __restrict__ ohi,
                                                  ushort_t* __restrict__ olo) {
  __shared__ float T[64][68];
  int t = threadIdx.x;
  int pix0 = blockIdx.x * 64, n0 = blockIdx.y * 64;
  int r = t >> 2, seg = t & 3;
  int pix = pix0 + r;
  int ri = pix >> 6, ci = pix & 63;
  float4 acc4[4];
#pragma unroll
  for (int j = 0; j < 4; ++j) acc4[j] = float4{0.f, 0.f, 0.f, 0.f};
#pragma unroll
  for (int di = 0; di < 3; ++di) {
    int ii = ri - di;
    if (ii < 0 || (ii & 1)) continue;
    int oi = ii >> 1;  if (oi >= 32) continue;
#pragma unroll
    for (int dj = 0; dj < 3; ++dj) {
      int jj = ci - dj;
      if (jj < 0 || (jj & 1)) continue;
      int oj = jj >> 1;  if (oj >= 32) continue;
      const float* row = ek + (size_t)((oi * 32 + oj) * 9 + di * 3 + dj) * GATES
                         + n0 + seg * 16;
#pragma unroll
      for (int j = 0; j < 4; ++j) {
        float4 v = *(const float4*)(row + j * 4);
        acc4[j].x += v.x; acc4[j].y += v.y; acc4[j].z += v.z; acc4[j].w += v.w;
      }
    }
  }
#pragma unroll
  for (int j = 0; j < 4; ++j) *(float4*)&T[r][seg * 16 + j * 4] = acc4[j];
  __syncthreads();
  ushort_t thi[16], tlo[16];
#pragma unroll
  for (int j = 0; j < 16; ++j) {
    float v = T[seg * 16 + j][r];
    ushort_t h = f2b(v);
    thi[j] = h;
    tlo[j] = f2b(v - b2f(h));
  }
  size_t off = (size_t)(n0 + r) * KENC + pix0 + seg * 16;
  *(uint4*)(ohi + off)     = *(const uint4*)&thi[0];
  *(uint4*)(ohi + off + 8) = *(const uint4*)&thi[8];
  *(uint4*)(olo + off)     = *(const uint4*)&tlo[0];
  *(uint4*)(olo + off + 8) = *(const uint4*)&tlo[8];
}

// ---------------------------------------------------------------------------
// Generic transpose + optional-sum + hi/lo split:
// out[n][koff+k] = split( s0[k][n] + (s1 ? s1[k][n] : 0) )
// grid: (krows/64, ncols/64)
// ---------------------------------------------------------------------------
__global__ __launch_bounds__(256) void k_prep_sum(const float* __restrict__ s0,
                                                  const float* __restrict__ s1,
                                                  int src_ld, int out_ld, int koff,
                                                  ushort_t* __restrict__ ohi,
                                                  ushort_t* __restrict__ olo) {
  __shared__ float T[64][68];
  int t = threadIdx.x;
  int k0 = blockIdx.x * 64, n0 = blockIdx.y * 64;
  int r = t >> 2, seg = t & 3;
  const float* src = s0 + (size_t)(k0 + r) * src_ld + n0 + seg * 16;
  const float* src2 = s1 ? (s1 + (size_t)(k0 + r) * src_ld + n0 + seg * 16) : nullptr;
#pragma unroll
  for (int j = 0; j < 4; ++j) {
    float4 v = *(const float4*)(src + j * 4);
    if (src2) {
      float4 w = *(const float4*)(src2 + j * 4);
      v.x += w.x; v.y += w.y; v.z += w.z; v.w += w.w;
    }
    *(float4*)&T[r][seg * 16 + j * 4] = v;
  }
  __syncthreads();
  ushort_t thi[16], tlo[16];
#pragma unroll
  for (int j = 0; j < 16; ++j) {
    float v = T[seg * 16 + j][r];
    ushort_t h = f2b(v);
    thi[j] = h;
    tlo[j] = f2b(v - b2f(h));
  }
  size_t off = (size_t)(n0 + r) * out_ld + koff + k0 + seg * 16;
  *(uint4*)(ohi + off)     = *(const uint4*)&thi[0];
  *(uint4*)(ohi + off + 8) = *(const uint4*)&thi[8];
  *(uint4*)(olo + off)     = *(const uint4*)&tlo[0];
  *(uint4*)(olo + off + 8) = *(const uint4*)&tlo[8];
}

// ---------------------------------------------------------------------------
// Step-0 x_hat: canvas==0 -> x_hat = x - 0.5
// ---------------------------------------------------------------------------
__global__ __launch_bounds__(256) void k_xhat0(const float* __restrict__ x,
                                               ushort_t* __restrict__ ehi,
                                               ushort_t* __restrict__ elo) {
  int tid = blockIdx.x * 256 + threadIdx.x;       // 512*4096
  int b = tid >> 12, pix = tid & 4095;
  float v = x[tid] - 0.5f;
  ushort_t h = f2b(v);
  ehi[(size_t)b * KENC + pix] = h;
  elo[(size_t)b * KENC + pix] = f2b(v - b2f(h));
}

// ---------------------------------------------------------------------------
// Fused 3-product split-precision GEMM: C[M,N] fp32 = A[M,K] * Bt[N,K]^T where
// A ~ Ahi+Alo, B ~ Bhi+Blo (bf16 hi/lo); hihi+hilo+lohi in one fp32 acc.
// 128x128 tile, 4 waves (2x2), 48 MFMA/kt/wave, double-buffered prefetch.
// Stores partial z to C + z*BSZ*ldc.
// ---------------------------------------------------------------------------
#define TM 128
#define TN 128
#define BK 32

#define GLL(g, l) __builtin_amdgcn_global_load_lds(                      \
    (const __attribute__((address_space(1))) void*)(g),                  \
    (__attribute__((address_space(3))) void*)(l), 16, 0, 0)

__global__ __launch_bounds__(256, 2) void gemm128(
    const ushort_t* __restrict__ Ahi, const ushort_t* __restrict__ Alo, int lda,
    const ushort_t* __restrict__ Bhi, const ushort_t* __restrict__ Blo, int ldbt,
    float* __restrict__ C, int ldc, int kiters) {
  __shared__ ushort_t ls[2][4][TM * BK];   // [buf][Ah,Al,Bh,Bl] : 64 KiB
  int t = threadIdx.x;
  int m0 = blockIdx.y * TM, n0 = blockIdx.x * TN;
  int z = blockIdx.z;
  int kstart = z * kiters * BK;
  int lane = t & 63, w = t >> 6;
  int wm = w >> 1, wn = w & 1;
  int q = lane >> 4, c16 = lane & 15;

  const ushort_t* pAh = Ahi + (size_t)(m0 + (t >> 2)) * lda + kstart + (t & 3) * 8;
  const ushort_t* pAl = Alo + (size_t)(m0 + (t >> 2)) * lda + kstart + (t & 3) * 8;
  const ushort_t* pBh = Bhi + (size_t)(n0 + (t >> 2)) * ldbt + kstart + (t & 3) * 8;
  const ushort_t* pBl = Blo + (size_t)(n0 + (t >> 2)) * ldbt + kstart + (t & 3) * 8;
  const size_t a64 = (size_t)64 * lda, b64 = (size_t)64 * ldbt;
  const int d0 = t * 8;

  floatx4 acc[4][4];
#pragma unroll
  for (int i = 0; i < 4; ++i)
#pragma unroll
    for (int j = 0; j < 4; ++j) acc[i][j] = floatx4{0.f, 0.f, 0.f, 0.f};

  GLL(pAh, &ls[0][0][d0]); GLL(pAh + a64, &ls[0][0][d0 + 2048]);
  GLL(pAl, &ls[0][1][d0]); GLL(pAl + a64, &ls[0][1][d0 + 2048]);
  GLL(pBh, &ls[0][2][d0]); GLL(pBh + b64, &ls[0][2][d0 + 2048]);
  GLL(pBl, &ls[0][3][d0]); GLL(pBl + b64, &ls[0][3][d0 + 2048]);
  pAh += BK; pAl += BK; pBh += BK; pBl += BK;
  __syncthreads();

  for (int kt = 0; kt < kiters; ++kt) {
    int cur = kt & 1, nxt = cur ^ 1;
    if (kt + 1 < kiters) {
      GLL(pAh, &ls[nxt][0][d0]); GLL(pAh + a64, &ls[nxt][0][d0 + 2048]);
      GLL(pAl, &ls[nxt][1][d0]); GLL(pAl + a64, &ls[nxt][1][d0 + 2048]);
      GLL(pBh, &ls[nxt][2][d0]); GLL(pBh + b64, &ls[nxt][2][d0 + 2048]);
      GLL(pBl, &ls[nxt][3][d0]); GLL(pBl + b64, &ls[nxt][3][d0 + 2048]);
      pAh += BK; pAl += BK; pBh += BK; pBl += BK;
    }
    short8 ah[4], al[4], bh[4], bl[4];
#pragma unroll
    for (int i = 0; i < 4; ++i) {
      int ra = (wm * 64 + i * 16 + c16) * BK + q * 8;
      int rb = (wn * 64 + i * 16 + c16) * BK + q * 8;
      ah[i] = *(const short8*)&ls[cur][0][ra];
      al[i] = *(const short8*)&ls[cur][1][ra];
      bh[i] = *(const short8*)&ls[cur][2][rb];
      bl[i] = *(const short8*)&ls[cur][3][rb];
    }
#pragma unroll
    for (int mi = 0; mi < 4; ++mi)
#pragma unroll
      for (int ni = 0; ni < 4; ++ni) {
        acc[mi][ni] = __builtin_amdgcn_mfma_f32_16x16x32_bf16(ah[mi], bh[ni], acc[mi][ni], 0, 0, 0);
        acc[mi][ni] = __builtin_amdgcn_mfma_f32_16x16x32_bf16(ah[mi], bl[ni], acc[mi][ni], 0, 0, 0);
        acc[mi][ni] = __builtin_amdgcn_mfma_f32_16x16x32_bf16(al[mi], bh[ni], acc[mi][ni], 0, 0, 0);
      }
    __syncthreads();
  }

  float* Cz = C + (size_t)z * BSZ * ldc;
#pragma unroll
  for (int mi = 0; mi < 4; ++mi)
#pragma unroll
    for (int ni = 0; ni < 4; ++ni) {
      int n = n0 + wn * 64 + ni * 16 + c16;
      int mb = m0 + wm * 64 + mi * 16 + q * 4;
#pragma unroll
      for (int r = 0; r < 4; ++r)
        Cz[(size_t)(mb + r) * ldc + n] = acc[mi][ni][r];
    }
}

// ---------------------------------------------------------------------------
// Canvas GEMM with fused x_hat epilogue:
// canvas[m][n] += (h_dec @ Wct^T)[m][n] + bdec[n];
// xh = x[m][n] - sigm(canvas[m][n]) -> ext hi/lo at [m][n] (pixel region)
// M=512, N=4096, K=256 (8 kt), grid (32, 4), no split-K.
// ---------------------------------------------------------------------------
__global__ __launch_bounds__(256, 2) void gemm_cv(
    const ushort_t* __restrict__ Ahi, const ushort_t* __restrict__ Alo, int lda,
    const ushort_t* __restrict__ Bhi, const ushort_t* __restrict__ Blo, int ldbt,
    float* __restrict__ canvas, const float* __restrict__ x,
    const float* __restrict__ bdec,
    ushort_t* __restrict__ ehi, ushort_t* __restrict__ elo) {
  __shared__ ushort_t ls[2][4][TM * BK];
  int t = threadIdx.x;
  int m0 = blockIdx.y * TM, n0 = blockIdx.x * TN;
  int lane = t & 63, w = t >> 6;
  int wm = w >> 1, wn = w & 1;
  int q = lane >> 4, c16 = lane & 15;
  const int kiters = 8;

  const ushort_t* pAh = Ahi + (size_t)(m0 + (t >> 2)) * lda + (t & 3) * 8;
  const ushort_t* pAl = Alo + (size_t)(m0 + (t >> 2)) * lda + (t & 3) * 8;
  const ushort_t* pBh = Bhi + (size_t)(n0 + (t >> 2)) * ldbt + (t & 3) * 8;
  const ushort_t* pBl = Blo + (size_t)(n0 + (t >> 2)) * ldbt + (t & 3) * 8;
  const size_t a64 = (size_t)64 * lda, b64 = (size_t)64 * ldbt;
  const int d0 = t * 8;

  floatx4 acc[4][4];
#pragma unroll
  for (int i = 0; i < 4; ++i)
#pragma unroll
    for (int j = 0; j < 4; ++j) acc[i][j] = floatx4{0.f, 0.f, 0.f, 0.f};

  GLL(pAh, &ls[0][0][d0]); GLL(pAh + a64, &ls[0][0][d0 + 2048]);
  GLL(pAl, &ls[0][1][d0]); GLL(pAl + a64, &ls[0][1][d0 + 2048]);
  GLL(pBh, &ls[0][2][d0]); GLL(pBh + b64, &ls[0][2][d0 + 2048]);
  GLL(pBl, &ls[0][3][d0]); GLL(pBl + b64, &ls[0][3][d0 + 2048]);
  pAh += BK; pAl += BK; pBh += BK; pBl += BK;
  __syncthreads();

  for (int kt = 0; kt < kiters; ++kt) {
    int cur = kt & 1, nxt = cur ^ 1;
    if (kt + 1 < kiters) {
      GLL(pAh, &ls[nxt][0][d0]); GLL(pAh + a64, &ls[nxt][0][d0 + 2048]);
      GLL(pAl, &ls[nxt][1][d0]); GLL(pAl + a64, &ls[nxt][1][d0 + 2048]);
      GLL(pBh, &ls[nxt][2][d0]); GLL(pBh + b64, &ls[nxt][2][d0 + 2048]);
      GLL(pBl, &ls[nxt][3][d0]); GLL(pBl + b64, &ls[nxt][3][d0 + 2048]);
      pAh += BK; pAl += BK; pBh += BK; pBl += BK;
    }
    short8 ah[4], al[4], bh[4], bl[4];
#pragma unroll
    for (int i = 0; i < 4; ++i) {
      int ra = (wm * 64 + i * 16 + c16) * BK + q * 8;
      int rb = (wn * 64 + i * 16 + c16) * BK + q * 8;
      ah[i] = *(const short8*)&ls[cur][0][ra];
      al[i] = *(const short8*)&ls[cur][1][ra];
      bh[i] = *(const short8*)&ls[cur][2][rb];
      bl[i] = *(const short8*)&ls[cur][3][rb];
    }
#pragma unroll
    for (int mi = 0; mi < 4; ++mi)
#pragma unroll
      for (int ni = 0; ni < 4; ++ni) {
        acc[mi][ni] = __builtin_amdgcn_mfma_f32_16x16x32_bf16(ah[mi], bh[ni], acc[mi][ni], 0, 0, 0);
        acc[mi][ni] = __builtin_amdgcn_mfma_f32_16x16x32_bf16(ah[mi], bl[ni], acc[mi][ni], 0, 0, 0);
        acc[mi][ni] = __builtin_amdgcn_mfma_f32_16x16x32_bf16(al[mi], bh[ni], acc[mi][ni], 0, 0, 0);
      }
    __syncthreads();
  }

#pragma unroll
  for (int mi = 0; mi < 4; ++mi)
#pragma unroll
    for (int ni = 0; ni < 4; ++ni) {
      int n = n0 + wn * 64 + ni * 16 + c16;
      int mb = m0 + wm * 64 + mi * 16 + q * 4;
      float bv = bdec[n];
#pragma unroll
      for (int r = 0; r < 4; ++r) {
        int m = mb + r;
        size_t idx = (size_t)m * 4096 + n;
        float cv = canvas[idx] + acc[mi][ni][r] + bv;
        canvas[idx] = cv;
        float xh = x[idx] - sigm(cv);
        ushort_t h = f2b(xh);
        ehi[(size_t)m * KENC + n] = h;
        elo[(size_t)m * KENC + n] = f2b(xh - b2f(h));
      }
    }
}

// ---------------------------------------------------------------------------
// Encoder LSTM elementwise + attention softmax + glimpse; block = batch row
// ---------------------------------------------------------------------------
__global__ __launch_bounds__(256) void k_enc(const float* __restrict__ zparts, int S,
                                             const float* __restrict__ ebias,
                                             float* __restrict__ c_enc,
                                             ushort_t* __restrict__ ehi,
                                             ushort_t* __restrict__ elo,
                                             const float* __restrict__ Wenc,
                                             const float* __restrict__ benc,
                                             ushort_t* __restrict__ dhi,
                                             ushort_t* __restrict__ dlo) {
  int b = blockIdx.x, u = threadIdx.x;
  float zi = ebias[u],       zf = ebias[u + 256];
  float zg = ebias[u + 512], zo = ebias[u + 768];
  for (int s = 0; s < S; ++s) {
    const float* z = zparts + ((size_t)s * BSZ + b) * GATES;
    zi += z[u]; zf += z[u + 256]; zg += z[u + 512]; zo += z[u + 768];
  }
  float c = c_enc[b * UNITS + u];
  float cn = sigm(zf) * c + sigm(zi) * tanhf(zg);
  float h = sigm(zo) * tanhf(cn);
  c_enc[b * UNITS + u] = cn;
  ushort_t hh = f2b(h);
  ehi[(size_t)b * KENC + 4352 + u] = hh;         // h_enc slot
  elo[(size_t)b * KENC + 4352 + u] = f2b(h - b2f(hh));

  __shared__ float sh[UNITS];
  __shared__ float slog[10];
  sh[u] = h;
  __syncthreads();
  if (u < 64) {
    float acc[10];
#pragma unroll
    for (int j = 0; j < 10; ++j) acc[j] = 0.f;
    for (int qq = 0; qq < 4; ++qq) {
      float hv = sh[u + qq * 64];
      const float* wr = Wenc + (u + qq * 64) * 10;
#pragma unroll
      for (int j = 0; j < 10; ++j) acc[j] += hv * wr[j];
    }
    for (int off = 32; off > 0; off >>= 1)
#pragma unroll
      for (int j = 0; j < 10; ++j) acc[j] += __shfl_down(acc[j], off);
    if (u == 0)
      for (int j = 0; j < 10; ++j) slog[j] = acc[j] + benc[j];
  }
  __syncthreads();
  float mx = slog[0];
  for (int j = 1; j < 10; ++j) mx = fmaxf(mx, slog[j]);
  float e[10], se = 0.f;
  for (int j = 0; j < 10; ++j) { e[j] = __expf(slog[j] - mx); se += e[j]; }
  float inv = 1.f / se;
  const float* wr = Wenc + u * 10;
  float zz = 0.f;
  for (int j = 0; j < 10; ++j) zz += e[j] * inv * wr[j];   // attn @ W_enc.T
  ushort_t zh = f2b(zz);
  dhi[(size_t)b * 512 + u] = zh;
  dlo[(size_t)b * 512 + u] = f2b(zz - b2f(zh));
}

// ---------------------------------------------------------------------------
// Decoder LSTM elementwise; writes h_dec (hi/lo) into dec_in and ext
// ---------------------------------------------------------------------------
__global__ __launch_bounds__(256) void k_dec(const float* __restrict__ zparts, int S,
                                             const float* __restrict__ dbias,
                                             float* __restrict__ c_dec,
                                             ushort_t* __restrict__ dhi,
                                             ushort_t* __restrict__ dlo,
                                             ushort_t* __restrict__ ehi,
                                             ushort_t* __restrict__ elo) {
  int b = blockIdx.x, u = threadIdx.x;
  float zi = dbias[u],       zf = dbias[u + 256];
  float zg = dbias[u + 512], zo = dbias[u + 768];
  for (int s = 0; s < S; ++s) {
    const float* z = zparts + ((size_t)s * BSZ + b) * GATES;
    zi += z[u]; zf += z[u + 256]; zg += z[u + 512]; zo += z[u + 768];
  }
  float c = c_dec[b * UNITS + u];
  float cn = sigm(zf) * c + sigm(zi) * tanhf(zg);
  float h = sigm(zo) * tanhf(cn);
  c_dec[b * UNITS + u] = cn;
  ushort_t hh = f2b(h);
  ushort_t hl = f2b(h - b2f(hh));
  dhi[(size_t)b * 512 + 256 + u] = hh;
  dlo[(size_t)b * 512 + 256 + u] = hl;
  ehi[(size_t)b * KENC + 4096 + u] = hh;         // h_dec slot (single, folded)
  elo[(size_t)b * KENC + 4096 + u] = hl;
}

// ---------------------------------------------------------------------------
extern "C" void kernel_launch(void* const* d_in, const int* in_sizes, int n_in,
                              void* d_out, int out_size, void* d_ws, size_t ws_size,
                              hipStream_t stream) {
  const float* x     = (const float*)d_in[0];
  const float* ek    = (const float*)d_in[1];   // [9728,1024]
  const float* er    = (const float*)d_in[2];   // [256,1024]
  const float* ebias = (const float*)d_in[3];
  const float* dk    = (const float*)d_in[4];   // [256,1024]
  const float* dr    = (const float*)d_in[5];   // [256,1024]
  const float* dbias = (const float*)d_in[6];
  const float* Wenc  = (const float*)d_in[7];   // [256,10]
  const float* benc  = (const float*)d_in[8];
  const float* Wdec  = (const float*)d_in[9];   // [256,4096]
  const float* bdec  = (const float*)d_in[10];

  float* canvas = (float*)d_out;                // [512, 4096] — persistent canvas

  char* p = (char*)d_ws;
  float* c_enc  = (float*)p;        p += (size_t)BSZ * UNITS * 4;
  float* c_dec  = (float*)p;        p += (size_t)BSZ * UNITS * 4;
  float* zep    = (float*)p;        p += (size_t)ESPLIT * BSZ * GATES * 4;
  float* zdp    = (float*)p;        p += (size_t)DSPLIT * BSZ * GATES * 4;
  ushort_t* ehi = (ushort_t*)p;     p += (size_t)BSZ * KENC * 2;
  ushort_t* elo = (ushort_t*)p;     p += (size_t)BSZ * KENC * 2;
  ushort_t* dhi = (ushort_t*)p;     p += (size_t)BSZ * 512 * 2;
  ushort_t* dlo = (ushort_t*)p;     p += (size_t)BSZ * 512 * 2;
  ushort_t* Wet_hi = (ushort_t*)p;  p += (size_t)GATES * KENC * 2;      // [1024][4608]
  ushort_t* Wet_lo = (ushort_t*)p;  p += (size_t)GATES * KENC * 2;
  ushort_t* Wdt_hi = (ushort_t*)p;  p += (size_t)GATES * 512 * 2;       // [1024][512]
  ushort_t* Wdt_lo = (ushort_t*)p;  p += (size_t)GATES * 512 * 2;
  ushort_t* Wct_hi = (ushort_t*)p;  p += (size_t)4096 * UNITS * 2;      // [4096][256]
  ushort_t* Wct_lo = (ushort_t*)p;  p += (size_t)4096 * UNITS * 2;

  hipMemsetAsync(canvas, 0, (size_t)BSZ * 4096 * 4, stream);
  hipMemsetAsync(c_enc,  0, (size_t)BSZ * UNITS * 4, stream);
  hipMemsetAsync(c_dec,  0, (size_t)BSZ * UNITS * 4, stream);
  hipMemsetAsync(ehi,    0, (size_t)BSZ * KENC * 2, stream);
  hipMemsetAsync(elo,    0, (size_t)BSZ * KENC * 2, stream);
  hipMemsetAsync(dhi,    0, (size_t)BSZ * 512 * 2, stream);
  hipMemsetAsync(dlo,    0, (size_t)BSZ * 512 * 2, stream);

  // ---- weight prep (once per launch) ----
  // pixel-folded encoder patch weights -> Wet[:, 0:4096)
  k_prep_pix<<<dim3(64, 16), 256, 0, stream>>>(ek, Wet_hi, Wet_lo);
  // h_dec fold: ek rows 9216..9471 + 9472..9727 -> Wet[:, 4096:4352)
  k_prep_sum<<<dim3(4, 16), 256, 0, stream>>>(ek + (size_t)9216 * GATES,
                                              ek + (size_t)9472 * GATES,
                                              GATES, KENC, 4096, Wet_hi, Wet_lo);
  // h_enc (recurrent): er -> Wet[:, 4352:4608)
  k_prep_sum<<<dim3(4, 16), 256, 0, stream>>>(er, nullptr, GATES, KENC, 4352,
                                              Wet_hi, Wet_lo);
  // decoder: dk -> Wdt[:, 0:256), dr -> Wdt[:, 256:512)
  k_prep_sum<<<dim3(4, 16), 256, 0, stream>>>(dk, nullptr, GATES, 512, 0,
                                              Wdt_hi, Wdt_lo);
  k_prep_sum<<<dim3(4, 16), 256, 0, stream>>>(dr, nullptr, GATES, 512, 256,
                                              Wdt_hi, Wdt_lo);
  // canvas: Wdec [256,4096] -> Wct [4096][256]
  k_prep_sum<<<dim3(4, 64), 256, 0, stream>>>(Wdec, nullptr, 4096, 256, 0,
                                              Wct_hi, Wct_lo);

  // step-0 x_hat (canvas = 0)
  k_xhat0<<<(BSZ * 4096) / 256, 256, 0, stream>>>(x, ehi, elo);

  for (int s = 0; s < STEPS; ++s) {
    // z_enc = ext @ Wet^T (M=512,K=4608,N=1024), fused 3-product, split-K 8x18
    gemm128<<<dim3(GATES / 128, BSZ / 128, ESPLIT), 256, 0, stream>>>(
        ehi, elo, KENC, Wet_hi, Wet_lo, KENC, zep, GATES, 18);
    k_enc<<<BSZ, 256, 0, stream>>>(zep, ESPLIT, ebias, c_enc, ehi, elo, Wenc, benc, dhi, dlo);
    // z_dec = [z|h_dec] @ Wdt^T (M=512,K=512,N=1024), split-K 4x4
    gemm128<<<dim3(GATES / 128, BSZ / 128, DSPLIT), 256, 0, stream>>>(
        dhi, dlo, 512, Wdt_hi, Wdt_lo, 512, zdp, GATES, 4);
    k_dec<<<BSZ, 256, 0, stream>>>(zdp, DSPLIT, dbias, c_dec, dhi, dlo, ehi, elo);
    // canvas += h_dec @ Wct^T + b_dec ; fused x_hat -> ext (M=512,N=4096,K=256)
    gemm_cv<<<dim3(4096 / 128, BSZ / 128), 256, 0, stream>>>(
        dhi + 256, dlo + 256, 512, Wct_hi, Wct_lo, 256, canvas, x, bdec, ehi, elo);
  }
}